// Round 14
// baseline (613.434 us; speedup 1.0000x reference)
//
#include <hip/hip_runtime.h>
#include <math.h>

#define NBANDS 31
#define FT 257000

typedef __attribute__((ext_vector_type(8))) short bh8;
typedef __attribute__((ext_vector_type(4))) float f4;

__constant__ int d_bs[NBANDS] = {0,1,1,2,2,2,3,3,4,5,6,7,8,10,11,13,16,19,23,27,32,38,45,54,64,76,91,108,128,152,181};
__constant__ int d_be[NBANDS] = {2,3,3,3,4,4,5,6,7,8,9,11,12,14,17,20,24,28,33,39,46,55,65,77,92,109,129,153,182,216,257};

__device__ __forceinline__ unsigned short b16u(float v) {
  __bf16 h = (__bf16)v;
  return __builtin_bit_cast(unsigned short, h);
}
__device__ __forceinline__ unsigned pk2(float a, float b) {
  return (unsigned)b16u(a) | ((unsigned)b16u(b) << 16);
}
__device__ __forceinline__ float hann1(int i, int L) {
  return 0.5f - 0.5f * cosf(6.283185307179586f * (float)i / (float)L);
}

// ---- weight f32 -> bf16 prep, permuted into MFMA-fragment order ----
__global__ __launch_bounds__(256) void prep_w(
    const float* __restrict__ enc_w, const float* __restrict__ dec_w,
    const float* __restrict__ qw, const float* __restrict__ kw,
    const float* __restrict__ vw, const float* __restrict__ ow,
    unsigned short* __restrict__ w16) {
  const int stride = gridDim.x * blockDim.x;
  for (int i = blockIdx.x * blockDim.x + threadIdx.x; i < 513024; i += stride) {
    float v;
    if (i < 190464) {                      // enc: K=64, KT=2
      const int k = i / 6144, r = i - k * 6144;
      const int tile = r >> 9, li = r & 511;
      const int lane = li >> 3, j = li & 7;
      const int g = lane >> 4, n = lane & 15;
      const int mt = tile >> 1, kt = tile & 1;
      v = enc_w[k * 6144 + (mt * 16 + n) * 64 + kt * 32 + g * 8 + j];
    } else if (i < 476160) {               // dec: K=96, KT=3
      const int i2 = i - 190464;
      const int k = i2 / 9216, r = i2 - k * 9216;
      const int tile = r >> 9, li = r & 511;
      const int lane = li >> 3, j = li & 7;
      const int g = lane >> 4, n = lane & 15;
      const int mt = tile / 3, kt = tile - mt * 3;
      v = dec_w[k * 9216 + (mt * 16 + n) * 96 + kt * 32 + g * 8 + j];
    } else {                               // q,k,v,o
      const int i2 = i - 476160;
      const int a = i2 / 9216, r = i2 - a * 9216;
      const int tile = r >> 9, li = r & 511;
      const int lane = li >> 3, j = li & 7;
      const int g = lane >> 4, n = lane & 15;
      const int mt = tile / 3, kt = tile - mt * 3;
      const float* src = (a == 0) ? qw : (a == 1) ? kw : (a == 2) ? vw : ow;
      v = src[(mt * 16 + n) * 96 + kt * 32 + g * 8 + j];
    }
    w16[i] = b16u(v);
  }
}

__global__ __launch_bounds__(192) void qp_kernel(const float* __restrict__ doa,
                                                 const float* __restrict__ dqg_w,
                                                 const float* __restrict__ dqg_b,
                                                 float* __restrict__ gbuf) {
  const int k = blockIdx.x, b = blockIdx.y;
  const int tid = threadIdx.x;
  __shared__ float sdoa[36];
  if (tid < 36) sdoa[tid] = doa[b * 36 + tid];
  __syncthreads();
  const float* wr = dqg_w + (k * 192 + tid) * 36;
  float acc = dqg_b[k * 192 + tid];
  #pragma unroll
  for (int i = 0; i < 36; ++i) acc = fmaf(wr[i], sdoa[i], acc);
  if (tid < 96) acc += 1.0f;
  gbuf[(k * 4 + b) * 192 + tid] = acc;
}

// ---- per-f table: {k0, nb, winv, win0..win4} ----
__global__ __launch_bounds__(320) void tab_kernel(float* __restrict__ ftab) {
  const int f = blockIdx.x * blockDim.x + threadIdx.x;
  if (f >= 257) return;
  int k0 = 0; while (d_be[k0] <= f) ++k0;
  int k1 = k0; while (k1 < NBANDS && d_bs[k1] <= f) ++k1;
  float wsum = 0.f, wn[5];
  for (int k = k0; k < k1; ++k) {
    const float wv = hann1(f - d_bs[k], d_be[k] - d_bs[k]);
    wn[k - k0] = wv; wsum += wv;
  }
  float* o = ftab + f * 8;
  o[0] = (float)k0; o[1] = (float)(k1 - k0); o[2] = 1.0f / fmaxf(wsum, 1e-8f);
  #pragma unroll
  for (int j = 0; j < 5; ++j) o[3 + j] = (j < k1 - k0) ? wn[j] : 0.f;
}

__device__ __forceinline__ void load3s(bh8* dst, const unsigned short* p, int step9) {
  #pragma unroll
  for (int m = 0; m < 3; ++m)
    dst[m] = *reinterpret_cast<const bh8*>(p + ((m * step9) << 9));
}

// cross-wave-pair LN over 96 chans (each wave holds 12 of its column's values)
__device__ __forceinline__ void ln96x(const f4* acc, const int h, const int col,
                                      const int g, float* red,
                                      float& mean, float& rs) {
  float s0 = 0.f, s1 = 0.f, q0 = 0.f, q1 = 0.f;
  #pragma unroll
  for (int m = 0; m < 3; ++m) {
    const float a0 = acc[m][0], a1 = acc[m][1], a2 = acc[m][2], a3 = acc[m][3];
    s0 += a0 + a2; s1 += a1 + a3;
    q0 = fmaf(a0, a0, q0); q1 = fmaf(a1, a1, q1);
    q0 = fmaf(a2, a2, q0); q1 = fmaf(a3, a3, q1);
  }
  float sm = s0 + s1, sq = q0 + q1;
  sm += __shfl_xor(sm, 16); sm += __shfl_xor(sm, 32);
  sq += __shfl_xor(sq, 16); sq += __shfl_xor(sq, 32);
  if (g == 0) { red[h * 128 + col] = sm; red[h * 128 + 64 + col] = sq; }
  __syncthreads();
  sm += red[(1 - h) * 128 + col];
  sq += red[(1 - h) * 128 + 64 + col];
  mean = sm * (1.f / 96.f);
  rs = rsqrtf(sq * (1.f / 96.f) - mean * mean + 1e-5f);
}

// ---- fused MFMA kernel; 8 waves (4 col-groups x 2 row-halves), 3 mt/wave ----
__global__ __launch_bounds__(512, 4) void fused_mfma(
    const float* __restrict__ mix, const float* __restrict__ spin,
    const unsigned short* __restrict__ enc16, const float* __restrict__ enc_b, const float* __restrict__ enc_a,
    const unsigned short* __restrict__ dec16, const float* __restrict__ dec_b, const float* __restrict__ dec_a,
    const float* __restrict__ gb, const float* __restrict__ ftab,
    const unsigned short* __restrict__ q16, const float* __restrict__ qb,
    const unsigned short* __restrict__ k16, const float* __restrict__ kb,
    const unsigned short* __restrict__ v16, const float* __restrict__ vb,
    const unsigned short* __restrict__ o16, const float* __restrict__ ob,
    float* __restrict__ out) {
  const int id0 = (int)blockIdx.x;
  const int id  = (id0 & 7) * 2056 + (id0 >> 3);   // bijective XCD swizzle (16448 = 8*2056)
  const int tt  = id & 15;
  const int fb  = id >> 4;
  const int f   = fb % 257;
  const int b   = fb / 257;
  const int t0  = tt << 6;

  const int tid  = threadIdx.x;
  const int lane = tid & 63;
  const int wv   = tid >> 6;      // 0..7
  const int cg   = wv & 3;        // column group
  const int h    = wv >> 2;       // row half: mt = h*3 + m
  const int g    = lane >> 4;
  const int n    = lane & 15;
  const int col  = (cg << 4) + n;
  const int t    = t0 + col;
  const bool tv  = t < 1000;
  const int tcl  = tv ? t : 999;
  const int sw   = (n & 7) << 3;
  const int lb   = lane << 3;
  const int oo   = g * 4;
  const int h48  = h * 48;
  const int hb2  = (h * 6) << 9;  // per-half enc tile offset (shorts)
  const int hb3  = (h * 9) << 9;  // per-half dec/qkvo tile offset

  // LDS pool: [XT 16384][stage 11776][red 2048]; OS (24960B) aliases from 0
  __shared__ __align__(16) char smem[30208];
  unsigned short* XT = (unsigned short*)smem;
  float* stage = (float*)(smem + 16384);
  float* red   = (float*)(smem + 28160);   // 512 floats: [LN1 256][LN2 256]
  float* OS    = (float*)smem;
  unsigned short* xw = XT + col * 128;

  const float* ft = ftab + f * 8;
  const int k0 = (int)ft[0];
  const int nb = (int)ft[1];
  const float winv = ft[2];

  // cooperative stage: per band (stride 512): encB96|decB96|gb192|ea,da,win ; tail: qb|kb|vb|ob
  {
    const int tot = (nb << 9) + 384;
    for (int i = tid; i < tot; i += 512) {
      const int kk = i >> 9, r = i & 511;
      float v = 0.f;
      if (kk < nb) {
        const int k = k0 + kk;
        if      (r < 96)  v = enc_b[k * 96 + r];
        else if (r < 192) v = dec_b[k * 96 + (r - 96)];
        else if (r < 384) v = gb[(k * 4 + b) * 192 + (r - 192)];
        else if (r == 384) v = enc_a[k];
        else if (r == 385) v = dec_a[k];
        else if (r == 386) v = ft[3 + kk];
      } else {
        const int r2 = i - (nb << 9);
        v = (r2 < 96) ? qb[r2] : (r2 < 192) ? kb[r2 - 96] : (r2 < 288) ? vb[r2 - 192] : ob[r2 - 288];
      }
      stage[i] = v;
    }
  }

  const float* spL = spin + b * 64 * FT + f * 1000 + tcl;
  const float* mxL = mix  + b * 96 * FT + f * 1000 + tcl;

  // spin prefetch (read-once; duplicated across halves, L1/L2-merged)
  bh8 spb[2];
  {
    float spf[16];
    #pragma unroll
    for (int j = 0; j < 8; ++j) spf[j]     = __builtin_nontemporal_load(spL + (g * 8 + j) * FT);
    #pragma unroll
    for (int j = 0; j < 8; ++j) spf[8 + j] = __builtin_nontemporal_load(spL + (32 + g * 8 + j) * FT);
    #pragma unroll
    for (int kt = 0; kt < 2; ++kt)
      #pragma unroll
      for (int j = 0; j < 8; ++j) spb[kt][j] = (short)b16u(spf[kt * 8 + j]);
  }

  // rotating prefetch buffer (3 tiles): enc g0 of first band, this half
  bh8 pre[3];
  load3s(pre, enc16 + k0 * 6144 + lb + hb2, 2);

  __syncthreads();   // stage visible

  f4 macc[3];
  #pragma unroll
  for (int m = 0; m < 3; ++m) macc[m] = (f4){0.f, 0.f, 0.f, 0.f};

  // ---------------- band loop; INV: pre = enc g0(k) of this half at entry ----------------
  for (int kk = 0; kk < nb; ++kk) {
    const int k = k0 + kk;
    const unsigned short* ewb = enc16 + k * 6144 + lb + hb2;
    const unsigned short* dwb = dec16 + k * 9216 + lb + hb3;
    const float* stg = stage + (kk << 9);

    // ---- enc: rows h48..h48+47; kt=0 from pre, kt=1 inline ----
    f4 acc[3];
    #pragma unroll
    for (int m = 0; m < 3; ++m) {
      const float4 bb = *reinterpret_cast<const float4*>(stg + h48 + m * 16 + oo);
      acc[m] = (f4){bb.x, bb.y, bb.z, bb.w};
    }
    #pragma unroll
    for (int m = 0; m < 3; ++m)
      acc[m] = __builtin_amdgcn_mfma_f32_16x16x32_bf16(pre[m], spb[0], acc[m], 0, 0, 0);
    #pragma unroll
    for (int m = 0; m < 3; ++m) {
      const bh8 af = *reinterpret_cast<const bh8*>(ewb + ((m * 2 + 1) << 9));
      acc[m] = __builtin_amdgcn_mfma_f32_16x16x32_bf16(af, spb[1], acc[m], 0, 0, 0);
    }

    // pre dead -> refill with dec g0 (hides under LN1 barrier/FiLM)
    load3s(pre, dwb, 3);

    float mean, rs;
    ln96x(acc, h, col, g, red, mean, rs);          // includes barrier
    const float ea = stg[384];
    #pragma unroll
    for (int m = 0; m < 3; ++m) {
      const float4 ga = *reinterpret_cast<const float4*>(stg + 192 + h48 + m * 16 + oo);
      const float4 be = *reinterpret_cast<const float4*>(stg + 288 + h48 + m * 16 + oo);
      float x0 = (acc[m][0] - mean) * rs; x0 = (x0 >= 0.f) ? x0 : ea * x0;
      float x1 = (acc[m][1] - mean) * rs; x1 = (x1 >= 0.f) ? x1 : ea * x1;
      float x2 = (acc[m][2] - mean) * rs; x2 = (x2 >= 0.f) ? x2 : ea * x2;
      float x3 = (acc[m][3] - mean) * rs; x3 = (x3 >= 0.f) ? x3 : ea * x3;
      uint2 u;
      u.x = pk2(fmaf(ga.x, x0, be.x), fmaf(ga.y, x1, be.y));
      u.y = pk2(fmaf(ga.z, x2, be.z), fmaf(ga.w, x3, be.w));
      *reinterpret_cast<uint2*>(xw + ((h48 + m * 16 + oo) ^ sw)) = u;
    }
    __syncthreads();   // full 96-chan tgt column visible

    // ---- dec: 96 chans from XT; kt=0 from pre ----
    f4 dacc[3];
    #pragma unroll
    for (int m = 0; m < 3; ++m) {
      const float4 bb = *reinterpret_cast<const float4*>(stg + 96 + h48 + m * 16 + oo);
      dacc[m] = (f4){bb.x, bb.y, bb.z, bb.w};
    }
    {
      const bh8 bf0 = *reinterpret_cast<const bh8*>(xw + ((g * 8) ^ sw));
      #pragma unroll
      for (int m = 0; m < 3; ++m)
        dacc[m] = __builtin_amdgcn_mfma_f32_16x16x32_bf16(pre[m], bf0, dacc[m], 0, 0, 0);
    }
    // pre dead -> refill with next band's enc g0 (or Q g0)
    {
      const bool more = (kk + 1 < nb);
      load3s(pre, more ? (enc16 + (k + 1) * 6144 + lb + hb2) : (q16 + lb + hb3), more ? 2 : 3);
    }
    #pragma unroll
    for (int kt = 1; kt < 3; ++kt) {
      const bh8 bf = *reinterpret_cast<const bh8*>(xw + ((kt * 32 + g * 8) ^ sw));
      #pragma unroll
      for (int m = 0; m < 3; ++m) {
        const bh8 af = *reinterpret_cast<const bh8*>(dwb + ((m * 3 + kt) << 9));
        dacc[m] = __builtin_amdgcn_mfma_f32_16x16x32_bf16(af, bf, dacc[m], 0, 0, 0);
      }
    }
    float mean2, rs2;
    ln96x(dacc, h, col, g, red + 256, mean2, rs2); // includes barrier
    const float da = stg[385];
    const float win = stg[386];
    #pragma unroll
    for (int m = 0; m < 3; ++m)
      #pragma unroll
      for (int r = 0; r < 4; ++r) {
        float x = (dacc[m][r] - mean2) * rs2;
        x = (x >= 0.f) ? x : da * x;
        macc[m][r] = fmaf(win, x, macc[m][r]);
      }
  }

  // ---- mix loads (full column; duplicated across halves, cached) ----
  float mxf[24];
  #pragma unroll
  for (int kt = 0; kt < 3; ++kt)
    #pragma unroll
    for (int j = 0; j < 8; ++j) mxf[kt * 8 + j] = mxL[(kt * 32 + g * 8 + j) * FT];

  // ---- merged -> XT ----
  #pragma unroll
  for (int m = 0; m < 3; ++m) {
    uint2 u;
    u.x = pk2(macc[m][0] * winv, macc[m][1] * winv);
    u.y = pk2(macc[m][2] * winv, macc[m][3] * winv);
    *reinterpret_cast<uint2*>(xw + ((h48 + m * 16 + oo) ^ sw)) = u;
  }
  __syncthreads();   // (A) merged column visible
  bh8 gfr[3];
  #pragma unroll
  for (int kt = 0; kt < 3; ++kt) gfr[kt] = *reinterpret_cast<const bh8*>(xw + ((kt * 32 + g * 8) ^ sw));

  bh8 mxb[3];
  #pragma unroll
  for (int kt = 0; kt < 3; ++kt)
    #pragma unroll
    for (int j = 0; j < 8; ++j) mxb[kt][j] = (short)b16u(mxf[kt * 8 + j]);

  const float* stQ = stage + (nb << 9);
  const unsigned short* qpb = q16 + lb + hb3;
  const unsigned short* kpb = k16 + lb + hb3;
  const unsigned short* vpb = v16 + lb + hb3;
  const unsigned short* opb = o16 + lb + hb3;

  // ---- Q: kt0 from pre; refill pre <- K g0 ----
  f4 qacc[3];
  #pragma unroll
  for (int m = 0; m < 3; ++m) {
    const float4 bb = *reinterpret_cast<const float4*>(stQ + h48 + m * 16 + oo);
    qacc[m] = (f4){bb.x, bb.y, bb.z, bb.w};
  }
  #pragma unroll
  for (int m = 0; m < 3; ++m)
    qacc[m] = __builtin_amdgcn_mfma_f32_16x16x32_bf16(pre[m], mxb[0], qacc[m], 0, 0, 0);
  load3s(pre, kpb, 3);
  #pragma unroll
  for (int kt = 1; kt < 3; ++kt)
    #pragma unroll
    for (int m = 0; m < 3; ++m) {
      const bh8 af = *reinterpret_cast<const bh8*>(qpb + ((m * 3 + kt) << 9));
      qacc[m] = __builtin_amdgcn_mfma_f32_16x16x32_bf16(af, mxb[kt], qacc[m], 0, 0, 0);
    }
  // ---- K: kt0 from pre; refill pre <- V g0 ----
  f4 kacc[3];
  #pragma unroll
  for (int m = 0; m < 3; ++m) {
    const float4 bb = *reinterpret_cast<const float4*>(stQ + 96 + h48 + m * 16 + oo);
    kacc[m] = (f4){bb.x, bb.y, bb.z, bb.w};
  }
  #pragma unroll
  for (int m = 0; m < 3; ++m)
    kacc[m] = __builtin_amdgcn_mfma_f32_16x16x32_bf16(pre[m], gfr[0], kacc[m], 0, 0, 0);
  load3s(pre, vpb, 3);
  #pragma unroll
  for (int kt = 1; kt < 3; ++kt)
    #pragma unroll
    for (int m = 0; m < 3; ++m) {
      const bh8 af = *reinterpret_cast<const bh8*>(kpb + ((m * 3 + kt) << 9));
      kacc[m] = __builtin_amdgcn_mfma_f32_16x16x32_bf16(af, gfr[kt], kacc[m], 0, 0, 0);
    }
  // cross-wave logit reduction (reuse LN1 red region)
  float p0 = 0.f, p1 = 0.f;
  #pragma unroll
  for (int m = 0; m < 3; ++m) {
    p0 = fmaf(qacc[m][0], kacc[m][0], p0);
    p1 = fmaf(qacc[m][1], kacc[m][1], p1);
    p0 = fmaf(qacc[m][2], kacc[m][2], p0);
    p1 = fmaf(qacc[m][3], kacc[m][3], p1);
  }
  float p = p0 + p1;
  p += __shfl_xor(p, 16); p += __shfl_xor(p, 32);
  if (g == 0) red[h * 128 + col] = p;
  __syncthreads();   // (B)
  p += red[(1 - h) * 128 + col];
  const float sig = 1.f / (1.f + __expf(-p * 0.10206207261596575f));

  // ---- V: kt0 from pre; refill pre <- O g0; attended -> XT ----
  f4 vacc[3];
  #pragma unroll
  for (int m = 0; m < 3; ++m) {
    const float4 bb = *reinterpret_cast<const float4*>(stQ + 192 + h48 + m * 16 + oo);
    vacc[m] = (f4){bb.x, bb.y, bb.z, bb.w};
  }
  #pragma unroll
  for (int m = 0; m < 3; ++m)
    vacc[m] = __builtin_amdgcn_mfma_f32_16x16x32_bf16(pre[m], gfr[0], vacc[m], 0, 0, 0);
  load3s(pre, opb, 3);
  #pragma unroll
  for (int kt = 1; kt < 3; ++kt)
    #pragma unroll
    for (int m = 0; m < 3; ++m) {
      const bh8 af = *reinterpret_cast<const bh8*>(vpb + ((m * 3 + kt) << 9));
      vacc[m] = __builtin_amdgcn_mfma_f32_16x16x32_bf16(af, gfr[kt], vacc[m], 0, 0, 0);
    }
  #pragma unroll
  for (int m = 0; m < 3; ++m) {
    uint2 u;
    u.x = pk2(vacc[m][0] * sig, vacc[m][1] * sig);
    u.y = pk2(vacc[m][2] * sig, vacc[m][3] * sig);
    *reinterpret_cast<uint2*>(xw + ((h48 + m * 16 + oo) ^ sw)) = u;
  }
  // residual loads (own rows only) — issue before the barrier
  float mres[3][4];
  #pragma unroll
  for (int m = 0; m < 3; ++m)
    #pragma unroll
    for (int r = 0; r < 4; ++r) mres[m][r] = mxL[(h48 + m * 16 + oo + r) * FT];
  __syncthreads();   // (C) attended column visible
  bh8 afr[3];
  #pragma unroll
  for (int kt = 0; kt < 3; ++kt) afr[kt] = *reinterpret_cast<const bh8*>(xw + ((kt * 32 + g * 8) ^ sw));

  // ---- O: kt0 from pre ----
  f4 oacc[3];
  #pragma unroll
  for (int m = 0; m < 3; ++m) {
    const float4 bb = *reinterpret_cast<const float4*>(stQ + 288 + h48 + m * 16 + oo);
    oacc[m] = (f4){bb.x, bb.y, bb.z, bb.w};
  }
  #pragma unroll
  for (int m = 0; m < 3; ++m)
    oacc[m] = __builtin_amdgcn_mfma_f32_16x16x32_bf16(pre[m], afr[0], oacc[m], 0, 0, 0);
  #pragma unroll
  for (int kt = 1; kt < 3; ++kt)
    #pragma unroll
    for (int m = 0; m < 3; ++m) {
      const bh8 af = *reinterpret_cast<const bh8*>(opb + ((m * 3 + kt) << 9));
      oacc[m] = __builtin_amdgcn_mfma_f32_16x16x32_bf16(af, afr[kt], oacc[m], 0, 0, 0);
    }

  __syncthreads();   // (D) all XT/stage reads done before aliased OS writes

  #pragma unroll
  for (int m = 0; m < 3; ++m)
    #pragma unroll
    for (int r = 0; r < 4; ++r)
      OS[(h48 + m * 16 + oo + r) * 65 + col] = mres[m][r] + oacc[m][r];

  __syncthreads();   // (E) OS complete

  // ---- block-coalesced full-line NT stores ----
  const int cvalid = 1000 - t0;
  #pragma unroll
  for (int it = 0; it < 12; ++it) {
    const int i   = it * 512 + tid;
    const int row = i >> 6;
    const int c   = i & 63;
    const float val = OS[row * 65 + c];
    if (c < cvalid)
      __builtin_nontemporal_store(val, out + (b * 96 + row) * FT + f * 1000 + t0 + c);
  }
}

extern "C" void kernel_launch(void* const* d_in, const int* in_sizes, int n_in,
                              void* d_out, int out_size, void* d_ws, size_t ws_size,
                              hipStream_t stream) {
  (void)in_sizes; (void)n_in; (void)out_size; (void)ws_size;
  const float* mix   = (const float*)d_in[0];
  const float* spin  = (const float*)d_in[1];
  const float* doa   = (const float*)d_in[2];
  const float* enc_w = (const float*)d_in[3];
  const float* enc_b = (const float*)d_in[4];
  const float* enc_a = (const float*)d_in[5];
  const float* dqg_w = (const float*)d_in[6];
  const float* dqg_b = (const float*)d_in[7];
  const float* dec_w = (const float*)d_in[8];
  const float* dec_b = (const float*)d_in[9];
  const float* dec_a = (const float*)d_in[10];
  const float* qw    = (const float*)d_in[11];
  const float* qb    = (const float*)d_in[12];
  const float* kw    = (const float*)d_in[13];
  const float* kb    = (const float*)d_in[14];
  const float* vw    = (const float*)d_in[15];
  const float* vb    = (const float*)d_in[16];
  const float* oww   = (const float*)d_in[17];
  const float* obb   = (const float*)d_in[18];
  float* outp = (float*)d_out;

  unsigned short* w16 = (unsigned short*)d_ws;
  unsigned short* enc16 = w16;                 // 31*6144
  unsigned short* dec16 = w16 + 190464;        // 31*9216
  unsigned short* q16   = w16 + 476160;
  unsigned short* k16   = q16 + 9216;
  unsigned short* v16   = k16 + 9216;
  unsigned short* o16   = v16 + 9216;
  float* gbws = (float*)((char*)d_ws + 1026048);  // 31*4*192 f32 (95232 B)
  float* ftab = (float*)((char*)d_ws + 1121280);  // 257*8 f32 (8224 B)

  hipLaunchKernelGGL(prep_w, dim3(512), dim3(256), 0, stream,
                     enc_w, dec_w, qw, kw, vw, oww, w16);
  hipLaunchKernelGGL(qp_kernel, dim3(NBANDS, 4), dim3(192), 0, stream,
                     doa, dqg_w, dqg_b, gbws);
  hipLaunchKernelGGL(tab_kernel, dim3(1), dim3(320), 0, stream, ftab);
  hipLaunchKernelGGL(fused_mfma, dim3(16448), dim3(512), 0, stream,
                     mix, spin, enc16, enc_b, enc_a, dec16, dec_b, dec_a, gbws, ftab,
                     q16, qb, k16, kb, v16, vb, o16, obb, outp);
}

// Round 15
// 544.285 us; speedup vs baseline: 1.1270x; 1.1270x over previous
//
#include <hip/hip_runtime.h>
#include <math.h>

#define NBANDS 31
#define FT 257000

typedef __attribute__((ext_vector_type(8))) short bh8;
typedef __attribute__((ext_vector_type(4))) float f4;

__constant__ int d_bs[NBANDS] = {0,1,1,2,2,2,3,3,4,5,6,7,8,10,11,13,16,19,23,27,32,38,45,54,64,76,91,108,128,152,181};
__constant__ int d_be[NBANDS] = {2,3,3,3,4,4,5,6,7,8,9,11,12,14,17,20,24,28,33,39,46,55,65,77,92,109,129,153,182,216,257};

__device__ __forceinline__ unsigned short b16u(float v) {
  __bf16 h = (__bf16)v;
  return __builtin_bit_cast(unsigned short, h);
}
__device__ __forceinline__ unsigned pk2(float a, float b) {
  return (unsigned)b16u(a) | ((unsigned)b16u(b) << 16);
}
__device__ __forceinline__ float hann1(int i, int L) {
  return 0.5f - 0.5f * cosf(6.283185307179586f * (float)i / (float)L);
}

// ---- weight f32 -> bf16 prep, permuted into MFMA-fragment order ----
__global__ __launch_bounds__(256) void prep_w(
    const float* __restrict__ enc_w, const float* __restrict__ dec_w,
    const float* __restrict__ qw, const float* __restrict__ kw,
    const float* __restrict__ vw, const float* __restrict__ ow,
    unsigned short* __restrict__ w16) {
  const int stride = gridDim.x * blockDim.x;
  for (int i = blockIdx.x * blockDim.x + threadIdx.x; i < 513024; i += stride) {
    float v;
    if (i < 190464) {                      // enc: K=64, KT=2
      const int k = i / 6144, r = i - k * 6144;
      const int tile = r >> 9, li = r & 511;
      const int lane = li >> 3, j = li & 7;
      const int g = lane >> 4, n = lane & 15;
      const int mt = tile >> 1, kt = tile & 1;
      v = enc_w[k * 6144 + (mt * 16 + n) * 64 + kt * 32 + g * 8 + j];
    } else if (i < 476160) {               // dec: K=96, KT=3
      const int i2 = i - 190464;
      const int k = i2 / 9216, r = i2 - k * 9216;
      const int tile = r >> 9, li = r & 511;
      const int lane = li >> 3, j = li & 7;
      const int g = lane >> 4, n = lane & 15;
      const int mt = tile / 3, kt = tile - mt * 3;
      v = dec_w[k * 9216 + (mt * 16 + n) * 96 + kt * 32 + g * 8 + j];
    } else {                               // q,k,v,o
      const int i2 = i - 476160;
      const int a = i2 / 9216, r = i2 - a * 9216;
      const int tile = r >> 9, li = r & 511;
      const int lane = li >> 3, j = li & 7;
      const int g = lane >> 4, n = lane & 15;
      const int mt = tile / 3, kt = tile - mt * 3;
      const float* src = (a == 0) ? qw : (a == 1) ? kw : (a == 2) ? vw : ow;
      v = src[(mt * 16 + n) * 96 + kt * 32 + g * 8 + j];
    }
    w16[i] = b16u(v);
  }
}

__global__ __launch_bounds__(192) void qp_kernel(const float* __restrict__ doa,
                                                 const float* __restrict__ dqg_w,
                                                 const float* __restrict__ dqg_b,
                                                 float* __restrict__ gbuf) {
  const int k = blockIdx.x, b = blockIdx.y;
  const int tid = threadIdx.x;
  __shared__ float sdoa[36];
  if (tid < 36) sdoa[tid] = doa[b * 36 + tid];
  __syncthreads();
  const float* wr = dqg_w + (k * 192 + tid) * 36;
  float acc = dqg_b[k * 192 + tid];
  #pragma unroll
  for (int i = 0; i < 36; ++i) acc = fmaf(wr[i], sdoa[i], acc);
  if (tid < 96) acc += 1.0f;
  gbuf[(k * 4 + b) * 192 + tid] = acc;
}

// ---- per-f table: {k0, nb, winv, win0..win4} ----
__global__ __launch_bounds__(320) void tab_kernel(float* __restrict__ ftab) {
  const int f = blockIdx.x * blockDim.x + threadIdx.x;
  if (f >= 257) return;
  int k0 = 0; while (d_be[k0] <= f) ++k0;
  int k1 = k0; while (k1 < NBANDS && d_bs[k1] <= f) ++k1;
  float wsum = 0.f, wn[5];
  for (int k = k0; k < k1; ++k) {
    const float wv = hann1(f - d_bs[k], d_be[k] - d_bs[k]);
    wn[k - k0] = wv; wsum += wv;
  }
  float* o = ftab + f * 8;
  o[0] = (float)k0; o[1] = (float)(k1 - k0); o[2] = 1.0f / fmaxf(wsum, 1e-8f);
  #pragma unroll
  for (int j = 0; j < 5; ++j) o[3 + j] = (j < k1 - k0) ? wn[j] : 0.f;
}

#define LDSWAIT asm volatile("s_waitcnt lgkmcnt(0)" ::: "memory")

__device__ __forceinline__ void init6(f4* acc, const float* s, int off) {
  #pragma unroll
  for (int mt = 0; mt < 6; ++mt) {
    const float4 bb = *reinterpret_cast<const float4*>(s + mt * 16 + off);
    acc[mt] = (f4){bb.x, bb.y, bb.z, bb.w};
  }
}
// tree-reduced LN over 24 per-lane values (+16/+32 shfl for 96-chan column)
__device__ __forceinline__ void ln96(const f4* acc, float& mean, float& rs) {
  float s0 = 0.f, s1 = 0.f, s2 = 0.f, s3 = 0.f;
  float q0 = 0.f, q1 = 0.f, q2 = 0.f, q3 = 0.f;
  #pragma unroll
  for (int mt = 0; mt < 6; ++mt) {
    const float a0 = acc[mt][0], a1 = acc[mt][1], a2 = acc[mt][2], a3 = acc[mt][3];
    s0 += a0; s1 += a1; s2 += a2; s3 += a3;
    q0 = fmaf(a0, a0, q0); q1 = fmaf(a1, a1, q1);
    q2 = fmaf(a2, a2, q2); q3 = fmaf(a3, a3, q3);
  }
  float sm = (s0 + s1) + (s2 + s3);
  float sq = (q0 + q1) + (q2 + q3);
  sm += __shfl_xor(sm, 16); sm += __shfl_xor(sm, 32);
  sq += __shfl_xor(sq, 16); sq += __shfl_xor(sq, 32);
  mean = sm * (1.f / 96.f);
  rs = rsqrtf(sq * (1.f / 96.f) - mean * mean + 1e-5f);
}
__device__ __forceinline__ void load6s(bh8* dst, const unsigned short* p, int step9) {
  #pragma unroll
  for (int mt = 0; mt < 6; ++mt)
    dst[mt] = *reinterpret_cast<const bh8*>(p + ((mt * step9) << 9));
}

// ---- fused MFMA kernel; aliased LDS; residual deferred to coalesced store loop ----
__global__ __launch_bounds__(256, 3) void fused_mfma(
    const float* __restrict__ mix, const float* __restrict__ spin,
    const unsigned short* __restrict__ enc16, const float* __restrict__ enc_b, const float* __restrict__ enc_a,
    const unsigned short* __restrict__ dec16, const float* __restrict__ dec_b, const float* __restrict__ dec_a,
    const float* __restrict__ gb, const float* __restrict__ ftab,
    const unsigned short* __restrict__ q16, const float* __restrict__ qb,
    const unsigned short* __restrict__ k16, const float* __restrict__ kb,
    const unsigned short* __restrict__ v16, const float* __restrict__ vb,
    const unsigned short* __restrict__ o16, const float* __restrict__ ob,
    float* __restrict__ out) {
  const int id0 = (int)blockIdx.x;
  const int id  = (id0 & 7) * 2056 + (id0 >> 3);   // bijective XCD swizzle (16448 = 8*2056)
  const int tt  = id & 15;
  const int fb  = id >> 4;
  const int f   = fb % 257;
  const int b   = fb / 257;
  const int t0  = tt << 6;

  const int tid  = threadIdx.x;
  const int lane = tid & 63;
  const int w    = tid >> 6;
  const int g    = lane >> 4;
  const int n    = lane & 15;
  const int col  = (w << 4) + n;
  const int t    = t0 + col;
  const int tcl  = (t < 1000) ? t : 999;
  const int sw   = (n & 7) << 3;
  const int lb   = lane << 3;

  // one LDS pool: [XT 16384B][stage 11776B]; OS (96*65*4=24960B) aliases from 0
  __shared__ __align__(16) char smem[28160];
  unsigned short* XT = (unsigned short*)smem;
  float* stage = (float*)(smem + 16384);
  float* OS = (float*)smem;
  unsigned short* xw = XT + col * 128;

  const float* ft = ftab + f * 8;
  const int k0 = (int)ft[0];
  const int nb = (int)ft[1];
  const float winv = ft[2];

  // cooperative stage: per band (stride 512): encB96|decB96|gb192|ea,da,win ; tail: qb|kb|vb|ob
  {
    const int tot = (nb << 9) + 384;
    for (int i = tid; i < tot; i += 256) {
      const int kk = i >> 9, r = i & 511;
      float v = 0.f;
      if (kk < nb) {
        const int k = k0 + kk;
        if      (r < 96)  v = enc_b[k * 96 + r];
        else if (r < 192) v = dec_b[k * 96 + (r - 96)];
        else if (r < 384) v = gb[(k * 4 + b) * 192 + (r - 192)];
        else if (r == 384) v = enc_a[k];
        else if (r == 385) v = dec_a[k];
        else if (r == 386) v = ft[3 + kk];
      } else {
        const int r2 = i - (nb << 9);
        v = (r2 < 96) ? qb[r2] : (r2 < 192) ? kb[r2 - 96] : (r2 < 288) ? vb[r2 - 192] : ob[r2 - 288];
      }
      stage[i] = v;
    }
  }

  const float* spL = spin + b * 64 * FT + f * 1000 + tcl;
  const float* mxL = mix  + b * 96 * FT + f * 1000 + tcl;

  // spin prefetch (read-once)
  bh8 spb[2];
  {
    float spf[16];
    #pragma unroll
    for (int j = 0; j < 8; ++j) spf[j]     = __builtin_nontemporal_load(spL + (g * 8 + j) * FT);
    #pragma unroll
    for (int j = 0; j < 8; ++j) spf[8 + j] = __builtin_nontemporal_load(spL + (32 + g * 8 + j) * FT);
    #pragma unroll
    for (int kt = 0; kt < 2; ++kt)
      #pragma unroll
      for (int j = 0; j < 8; ++j) spb[kt][j] = (short)b16u(spf[kt * 8 + j]);
  }

  // rotating prefetch buffer: enc g0 of first band
  bh8 pre[6];
  load6s(pre, enc16 + k0 * 6144 + lb, 2);

  __syncthreads();   // stage visible

  f4 macc[6];
  #pragma unroll
  for (int mt = 0; mt < 6; ++mt) macc[mt] = (f4){0.f, 0.f, 0.f, 0.f};

  const int oo = g * 4;

  // ---------------- band loop; INV: pre = enc g0(k) at entry ----------------
  for (int kk = 0; kk < nb; ++kk) {
    const int k = k0 + kk;
    const unsigned short* ew  = enc16 + k * 6144 + lb;
    const unsigned short* dwp = dec16 + k * 9216 + lb;
    const float* stg = stage + (kk << 9);

    // ---- enc: 96x64; kt=0 from pre, kt=1 inline ----
    f4 acc[6];
    init6(acc, stg, oo);
    #pragma unroll
    for (int mt = 0; mt < 6; ++mt)
      acc[mt] = __builtin_amdgcn_mfma_f32_16x16x32_bf16(pre[mt], spb[0], acc[mt], 0, 0, 0);
    #pragma unroll
    for (int mt = 0; mt < 6; ++mt) {
      const bh8 af = *reinterpret_cast<const bh8*>(ew + ((mt * 2 + 1) << 9));
      acc[mt] = __builtin_amdgcn_mfma_f32_16x16x32_bf16(af, spb[1], acc[mt], 0, 0, 0);
    }

    // pre dead -> refill with dec g0 (hides under LN1/FiLM)
    load6s(pre, dwp, 3);

    float mean, rs;
    ln96(acc, mean, rs);
    const float ea = stg[384];
    #pragma unroll
    for (int mt = 0; mt < 6; ++mt) {
      const float4 ga = *reinterpret_cast<const float4*>(stg + 192 + mt * 16 + oo);
      const float4 be = *reinterpret_cast<const float4*>(stg + 288 + mt * 16 + oo);
      float x0 = (acc[mt][0] - mean) * rs; x0 = (x0 >= 0.f) ? x0 : ea * x0;
      float x1 = (acc[mt][1] - mean) * rs; x1 = (x1 >= 0.f) ? x1 : ea * x1;
      float x2 = (acc[mt][2] - mean) * rs; x2 = (x2 >= 0.f) ? x2 : ea * x2;
      float x3 = (acc[mt][3] - mean) * rs; x3 = (x3 >= 0.f) ? x3 : ea * x3;
      uint2 u;
      u.x = pk2(fmaf(ga.x, x0, be.x), fmaf(ga.y, x1, be.y));
      u.y = pk2(fmaf(ga.z, x2, be.z), fmaf(ga.w, x3, be.w));
      *reinterpret_cast<uint2*>(xw + ((mt * 16 + g * 4) ^ sw)) = u;
    }
    LDSWAIT;

    // ---- dec: 96x96 from XT; kt=0 from pre ----
    f4 dacc[6];
    init6(dacc, stg + 96, oo);
    {
      const bh8 bf0 = *reinterpret_cast<const bh8*>(xw + ((0 * 32 + g * 8) ^ sw));
      #pragma unroll
      for (int mt = 0; mt < 6; ++mt)
        dacc[mt] = __builtin_amdgcn_mfma_f32_16x16x32_bf16(pre[mt], bf0, dacc[mt], 0, 0, 0);
    }

    // pre dead -> refill with next band's enc g0 (or Q g0)
    {
      const bool more = (kk + 1 < nb);
      load6s(pre, more ? (enc16 + (k + 1) * 6144 + lb) : (q16 + lb), more ? 2 : 3);
    }

    #pragma unroll
    for (int kt = 1; kt < 3; ++kt) {
      const bh8 bf = *reinterpret_cast<const bh8*>(xw + ((kt * 32 + g * 8) ^ sw));
      #pragma unroll
      for (int mt = 0; mt < 6; ++mt) {
        const bh8 af = *reinterpret_cast<const bh8*>(dwp + ((mt * 3 + kt) << 9));
        dacc[mt] = __builtin_amdgcn_mfma_f32_16x16x32_bf16(af, bf, dacc[mt], 0, 0, 0);
      }
    }
    float mean2, rs2;
    ln96(dacc, mean2, rs2);
    const float da = stg[385];
    const float win = stg[386];
    #pragma unroll
    for (int mt = 0; mt < 6; ++mt)
      #pragma unroll
      for (int r = 0; r < 4; ++r) {
        float x = (dacc[mt][r] - mean2) * rs2;
        x = (x >= 0.f) ? x : da * x;
        macc[mt][r] = fmaf(win, x, macc[mt][r]);
      }
  }

  // ---- mix loads (cached; fragment pass) ----
  float mxf[24];
  #pragma unroll
  for (int kt = 0; kt < 3; ++kt)
    #pragma unroll
    for (int j = 0; j < 8; ++j) mxf[kt * 8 + j] = mxL[(kt * 32 + g * 8 + j) * FT];

  // ---- merged -> XT ----
  #pragma unroll
  for (int mt = 0; mt < 6; ++mt) {
    uint2 u;
    u.x = pk2(macc[mt][0] * winv, macc[mt][1] * winv);
    u.y = pk2(macc[mt][2] * winv, macc[mt][3] * winv);
    *reinterpret_cast<uint2*>(xw + ((mt * 16 + g * 4) ^ sw)) = u;
  }
  LDSWAIT;
  bh8 gfr[3];
  #pragma unroll
  for (int kt = 0; kt < 3; ++kt) gfr[kt] = *reinterpret_cast<const bh8*>(xw + ((kt * 32 + g * 8) ^ sw));

  bh8 mxb[3];
  #pragma unroll
  for (int kt = 0; kt < 3; ++kt)
    #pragma unroll
    for (int j = 0; j < 8; ++j) mxb[kt][j] = (short)b16u(mxf[kt * 8 + j]);

  const float* stQ = stage + (nb << 9);

  // ---- Q: kt0 from pre; refill pre <- K g0 ----
  f4 qacc[6];
  init6(qacc, stQ, oo);
  const unsigned short* qp16 = q16 + lb;
  #pragma unroll
  for (int mt = 0; mt < 6; ++mt)
    qacc[mt] = __builtin_amdgcn_mfma_f32_16x16x32_bf16(pre[mt], mxb[0], qacc[mt], 0, 0, 0);
  load6s(pre, k16 + lb, 3);
  #pragma unroll
  for (int kt = 1; kt < 3; ++kt)
    #pragma unroll
    for (int mt = 0; mt < 6; ++mt) {
      const bh8 af = *reinterpret_cast<const bh8*>(qp16 + ((mt * 3 + kt) << 9));
      qacc[mt] = __builtin_amdgcn_mfma_f32_16x16x32_bf16(af, mxb[kt], qacc[mt], 0, 0, 0);
    }
  // ---- K: kt0 from pre; refill pre <- V g0 ----
  f4 kacc[6];
  init6(kacc, stQ + 96, oo);
  const unsigned short* kp16 = k16 + lb;
  #pragma unroll
  for (int mt = 0; mt < 6; ++mt)
    kacc[mt] = __builtin_amdgcn_mfma_f32_16x16x32_bf16(pre[mt], gfr[0], kacc[mt], 0, 0, 0);
  load6s(pre, v16 + lb, 3);
  #pragma unroll
  for (int kt = 1; kt < 3; ++kt)
    #pragma unroll
    for (int mt = 0; mt < 6; ++mt) {
      const bh8 af = *reinterpret_cast<const bh8*>(kp16 + ((mt * 3 + kt) << 9));
      kacc[mt] = __builtin_amdgcn_mfma_f32_16x16x32_bf16(af, gfr[kt], kacc[mt], 0, 0, 0);
    }
  float p0 = 0.f, p1 = 0.f;
  #pragma unroll
  for (int mt = 0; mt < 6; ++mt) {
    p0 = fmaf(qacc[mt][0], kacc[mt][0], p0);
    p1 = fmaf(qacc[mt][1], kacc[mt][1], p1);
    p0 = fmaf(qacc[mt][2], kacc[mt][2], p0);
    p1 = fmaf(qacc[mt][3], kacc[mt][3], p1);
  }
  float p = p0 + p1;
  p += __shfl_xor(p, 16); p += __shfl_xor(p, 32);
  const float sig = 1.f / (1.f + __expf(-p * 0.10206207261596575f));

  // ---- V: kt0 from pre; refill pre <- O g0 ----
  f4 vacc[6];
  init6(vacc, stQ + 192, oo);
  const unsigned short* vp16 = v16 + lb;
  #pragma unroll
  for (int mt = 0; mt < 6; ++mt)
    vacc[mt] = __builtin_amdgcn_mfma_f32_16x16x32_bf16(pre[mt], gfr[0], vacc[mt], 0, 0, 0);
  load6s(pre, o16 + lb, 3);
  #pragma unroll
  for (int kt = 1; kt < 3; ++kt)
    #pragma unroll
    for (int mt = 0; mt < 6; ++mt) {
      const bh8 af = *reinterpret_cast<const bh8*>(vp16 + ((mt * 3 + kt) << 9));
      vacc[mt] = __builtin_amdgcn_mfma_f32_16x16x32_bf16(af, gfr[kt], vacc[mt], 0, 0, 0);
    }
  #pragma unroll
  for (int mt = 0; mt < 6; ++mt) {
    uint2 u;
    u.x = pk2(vacc[mt][0] * sig, vacc[mt][1] * sig);
    u.y = pk2(vacc[mt][2] * sig, vacc[mt][3] * sig);
    *reinterpret_cast<uint2*>(xw + ((mt * 16 + g * 4) ^ sw)) = u;
  }
  LDSWAIT;
  bh8 afr[3];
  #pragma unroll
  for (int kt = 0; kt < 3; ++kt) afr[kt] = *reinterpret_cast<const bh8*>(xw + ((kt * 32 + g * 8) ^ sw));

  // ---- O: kt0 from pre ----
  f4 oacc[6];
  init6(oacc, stQ + 288, oo);
  const unsigned short* op16 = o16 + lb;
  #pragma unroll
  for (int mt = 0; mt < 6; ++mt)
    oacc[mt] = __builtin_amdgcn_mfma_f32_16x16x32_bf16(pre[mt], afr[0], oacc[mt], 0, 0, 0);
  #pragma unroll
  for (int kt = 1; kt < 3; ++kt)
    #pragma unroll
    for (int mt = 0; mt < 6; ++mt) {
      const bh8 af = *reinterpret_cast<const bh8*>(op16 + ((mt * 3 + kt) << 9));
      oacc[mt] = __builtin_amdgcn_mfma_f32_16x16x32_bf16(af, afr[kt], oacc[mt], 0, 0, 0);
    }

  __syncthreads();   // ALL waves done with XT/stage before aliased OS writes

  #pragma unroll
  for (int mt = 0; mt < 6; ++mt)
    #pragma unroll
    for (int r = 0; r < 4; ++r)
      OS[(mt * 16 + g * 4 + r) * 65 + col] = oacc[mt][r];

  __syncthreads();   // all waves' OS writes visible

  // ---- block-coalesced: read residual (L2-hot full lines) + add + NT store ----
  const int cvalid = 1000 - t0;   // valid columns in this tile
  #pragma unroll
  for (int it = 0; it < 24; ++it) {
    const int i   = it * 256 + tid;
    const int row = i >> 6;
    const int c   = i & 63;
    if (c < cvalid) {
      const long gi = (long)(b * 96 + row) * FT + f * 1000 + t0 + c;
      const float val = OS[row * 65 + c] + mix[gi];
      __builtin_nontemporal_store(val, out + gi);
    }
  }
}

extern "C" void kernel_launch(void* const* d_in, const int* in_sizes, int n_in,
                              void* d_out, int out_size, void* d_ws, size_t ws_size,
                              hipStream_t stream) {
  (void)in_sizes; (void)n_in; (void)out_size; (void)ws_size;
  const float* mix   = (const float*)d_in[0];
  const float* spin  = (const float*)d_in[1];
  const float* doa   = (const float*)d_in[2];
  const float* enc_w = (const float*)d_in[3];
  const float* enc_b = (const float*)d_in[4];
  const float* enc_a = (const float*)d_in[5];
  const float* dqg_w = (const float*)d_in[6];
  const float* dqg_b = (const float*)d_in[7];
  const float* dec_w = (const float*)d_in[8];
  const float* dec_b = (const float*)d_in[9];
  const float* dec_a = (const float*)d_in[10];
  const float* qw    = (const float*)d_in[11];
  const float* qb    = (const float*)d_in[12];
  const float* kw    = (const float*)d_in[13];
  const float* kb    = (const float*)d_in[14];
  const float* vw    = (const float*)d_in[15];
  const float* vb    = (const float*)d_in[16];
  const float* oww   = (const float*)d_in[17];
  const float* obb   = (const float*)d_in[18];
  float* outp = (float*)d_out;

  unsigned short* w16 = (unsigned short*)d_ws;
  unsigned short* enc16 = w16;                 // 31*6144
  unsigned short* dec16 = w16 + 190464;        // 31*9216
  unsigned short* q16   = w16 + 476160;
  unsigned short* k16   = q16 + 9216;
  unsigned short* v16   = k16 + 9216;
  unsigned short* o16   = v16 + 9216;
  float* gbws = (float*)((char*)d_ws + 1026048);  // 31*4*192 f32 (95232 B)
  float* ftab = (float*)((char*)d_ws + 1121280);  // 257*8 f32 (8224 B)

  hipLaunchKernelGGL(prep_w, dim3(512), dim3(256), 0, stream,
                     enc_w, dec_w, qw, kw, vw, oww, w16);
  hipLaunchKernelGGL(qp_kernel, dim3(NBANDS, 4), dim3(192), 0, stream,
                     doa, dqg_w, dqg_b, gbws);
  hipLaunchKernelGGL(tab_kernel, dim3(1), dim3(320), 0, stream, ftab);
  hipLaunchKernelGGL(fused_mfma, dim3(16448), dim3(256), 0, stream,
                     mix, spin, enc16, enc_b, enc_a, dec16, dec_b, dec_a, gbws, ftab,
                     q16, qb, k16, kb, v16, vb, o16, obb, outp);
}